// Round 9
// baseline (398.955 us; speedup 1.0000x reference)
//
#include <hip/hip_runtime.h>
#include <math.h>

#define TPB      128
#define NBLOCKS  512
#define BATCHN   8192
#define NMAT     4
#define PERS     24
#define NK       201
#define NPG      512
#define DSTR     124     // drift bounce row stride (halves)
#define HSTR     76      // hedge bounce row stride (halves)
#define GSC      (1.0f/4096.0f)
#define GUNSC    4096.0f

typedef _Float16 f16;
typedef _Float16 f16x4 __attribute__((ext_vector_type(4)));
typedef _Float16 f16x8 __attribute__((ext_vector_type(8)));
typedef float    f32x4 __attribute__((ext_vector_type(4)));

#define LDS_FENCE() asm volatile("s_waitcnt lgkmcnt(0)" ::: "memory")

__device__ __forceinline__ f16x8 relu8(f16x8 v){
#pragma unroll
  for (int i = 0; i < 8; ++i) v[i] = (v[i] > (f16)0.f) ? v[i] : (f16)0.f;
  return v;
}
__device__ __forceinline__ f16x8 cvt88(float4 a, float4 b){
  f16x8 r;
  r[0]=(f16)a.x; r[1]=(f16)a.y; r[2]=(f16)a.z; r[3]=(f16)a.w;
  r[4]=(f16)b.x; r[5]=(f16)b.y; r[6]=(f16)b.z; r[7]=(f16)b.w;
  return r;
}
__device__ __forceinline__ f16x4 cvt4(float4 a){
  f16x4 r; r[0]=(f16)a.x; r[1]=(f16)a.y; r[2]=(f16)a.z; r[3]=(f16)a.w; return r;
}
// x/(1+|x|*s) via v_rcp_f32 (1-ulp approx; threshold budget is ~6.5e6)
__device__ __forceinline__ float sdiv(float x, float s){
  return x * __builtin_amdgcn_rcpf(fmaf(fabsf(x), s, 1.f));
}

__global__ __launch_bounds__(TPB, 1)
void sde_kernel(const float* __restrict__ nW0, const float* __restrict__ nb0,
                const float* __restrict__ nW1, const float* __restrict__ nb1,
                const float* __restrict__ nW2, const float* __restrict__ nb2,
                const float* __restrict__ nW3, const float* __restrict__ nb3,
                const float* __restrict__ hW0, const float* __restrict__ hb0,
                const float* __restrict__ hW1, const float* __restrict__ hb1,
                const float* __restrict__ hW2, const float* __restrict__ hb2,
                const float* __restrict__ hW3, const float* __restrict__ hb3,
                const float* __restrict__ hW4, const float* __restrict__ hb4,
                const float* __restrict__ rho, const float* __restrict__ V0,
                const float* __restrict__ strikes,
                const float* __restrict__ noise1, const float* __restrict__ noise2,
                float* __restrict__ part1, float* __restrict__ part2)
{
  __shared__ __align__(16) f16   bbD[16*DSTR];        // drift bounce (wave0)
  __shared__ __align__(16) f16   bbH[4][16*HSTR];     // hedge bounces (wave1, 2 sets)
  __shared__ float SP[2][PERS][16], CP[2][PERS][16];  // period buffers (dbuf)
  __shared__ float SfinAll[NMAT][16], CstAll[NMAT][16];
  __shared__ float Gsave[NMAT][64][17];               // wave1-private G store

  const int tid  = threadIdx.x;
  const int wv   = tid >> 6;
  const int lane = tid & 63;
  const int L15  = lane & 15;
  const int G    = lane >> 4;
  const int gpath = blockIdx.x * 16 + L15;

  const float DTf = (float)(2.0/96.0);
  const float SDT = 0.14433756729740643f;
  const float DFf = (float)exp(-0.05 * 2.0 / 96.0);
  const float rho_s = rho[0];
  const float rt1m  = sqrtf(1.f - rho_s*rho_s);

  float S = 100.f, Vv = V0[0];   // wave0 scan state

  // ---------------- producer: drift scan for maturity m ----------------
  auto produce = [&](int m){
    f16x8 aD1[6], aD2[6];  f32x4 bD1r[6], bD2r[6], w3r[6];
    f16x8 w0r[3][4];
#pragma unroll
    for (int t6 = 0; t6 < 6; ++t6){
      const int n  = t6 >> 1;
      const int o  = ((t6 & 1) << 4) + L15;
      const int ob = ((t6 & 1) << 4) + 4*G;
      const float* p1 = nW1 + (size_t)(((n*4+m)*32)+o)*32 + G*8;
      aD1[t6] = cvt88(*(const float4*)p1, *(const float4*)(p1+4));
      const float* p2 = nW2 + (size_t)(((n*4+m)*32)+o)*32 + G*8;
      aD2[t6] = cvt88(*(const float4*)p2, *(const float4*)(p2+4));
      bD1r[t6] = *(const f32x4*)(nb1 + (n*4+m)*32 + ob);
      bD2r[t6] = *(const f32x4*)(nb2 + (n*4+m)*32 + ob);
      w3r[t6]  = *(const f32x4*)(nW3 + (n*4+m)*32 + ob);
    }
    const float b30 = nb3[m], b31 = nb3[4+m], b32 = nb3[8+m];
#pragma unroll
    for (int n = 0; n < 3; ++n){
      f16x8 wt, ws, wvv, bz;
#pragma unroll
      for (int j = 0; j < 8; ++j){
        const int o = G*8 + j;
        const float* p = nW0 + (size_t)(((n*4+m)*32)+o)*3;
        wt[j]=(f16)p[0]; ws[j]=(f16)p[1]; wvv[j]=(f16)p[2];
        bz[j]=(f16)nb0[(n*4+m)*32+o];
      }
      w0r[n][0]=wt; w0r[n][1]=ws; w0r[n][2]=wvv; w0r[n][3]=bz;
    }
    float pn1 = noise1[(size_t)(m*PERS)*BATCHN + gpath];
    float pn2 = noise2[(size_t)(m*PERS)*BATCHN + gpath];
    float Cacc = 0.f;
    const int b = m & 1;

#pragma unroll 1
    for (int s = 0; s < PERS; ++s){
      const int gstep = m*PERS + s;
      const float t = (float)gstep * DTf;
      float nn1 = 0.f, nn2 = 0.f;
      if (s+1 < PERS){
        nn1 = noise1[(size_t)(gstep+1)*BATCHN + gpath];
        nn2 = noise2[(size_t)(gstep+1)*BATCHN + gpath];
      }
      const f16 th=(f16)t, Sh=(f16)S, Vh=(f16)Vv;
      f16x8 bfr[3];
#pragma unroll
      for (int n = 0; n < 3; ++n)
        bfr[n] = relu8(w0r[n][0]*th + w0r[n][1]*Sh + w0r[n][2]*Vh + w0r[n][3]);
#pragma unroll
      for (int t6 = 0; t6 < 6; ++t6){
        f32x4 acc = {bD1r[t6][0], bD1r[t6][1], bD1r[t6][2], bD1r[t6][3]};
        acc = __builtin_amdgcn_mfma_f32_16x16x32_f16(aD1[t6], bfr[t6>>1], acc, 0,0,0);
        f16x4 o4;
        o4[0]=(f16)fmaxf(acc[0],0.f); o4[1]=(f16)fmaxf(acc[1],0.f);
        o4[2]=(f16)fmaxf(acc[2],0.f); o4[3]=(f16)fmaxf(acc[3],0.f);
        *(f16x4*)&bbD[L15*DSTR + t6*16 + 4*G] = o4;
      }
      LDS_FENCE();
      f16x8 bl[3];
#pragma unroll
      for (int n = 0; n < 3; ++n)
        bl[n] = *(const f16x8*)&bbD[L15*DSTR + n*32 + G*8];
      f32x4 c2[6];
#pragma unroll
      for (int t6 = 0; t6 < 6; ++t6){
        f32x4 acc = {bD2r[t6][0], bD2r[t6][1], bD2r[t6][2], bD2r[t6][3]};
        c2[t6] = __builtin_amdgcn_mfma_f32_16x16x32_f16(aD2[t6], bl[t6>>1], acc, 0,0,0);
      }
      float pr0=0.f, pr1=0.f, pr2=0.f;
#pragma unroll
      for (int t6 = 0; t6 < 6; ++t6){
        const f32x4 w4 = w3r[t6];
        const float pp = w4[0]*fmaxf(c2[t6][0],0.f)+w4[1]*fmaxf(c2[t6][1],0.f)
                       + w4[2]*fmaxf(c2[t6][2],0.f)+w4[3]*fmaxf(c2[t6][3],0.f);
        if (t6<2) pr0+=pp; else if (t6<4) pr1+=pp; else pr2+=pp;
      }
      pr0 += __shfl_xor(pr0,16); pr0 += __shfl_xor(pr0,32);
      pr1 += __shfl_xor(pr1,16); pr1 += __shfl_xor(pr1,32);
      pr2 += __shfl_xor(pr2,16); pr2 += __shfl_xor(pr2,32);
      const float sigS = sdiv(pr0 + b30, SDT);
      const float bV   = sdiv(pr1 + b31, SDT);
      const float sigV = sdiv(pr2 + b32, SDT);
      const float bS   = sdiv(S*0.05f, SDT);
      const float dW = SDT*pn2;
      const float dB = rho_s*dW + rt1m*SDT*pn1;
      const float c  = DFf*S*sigS*dW;
      Cacc += c;
      if (G == 0){ SP[b][s][L15] = S; CP[b][s][L15] = c; }
      S  = S + bS*DTf + sigS*dB;
      Vv = fmaxf(Vv + bV*DTf + sigV*dW, 0.f);
      pn1 = nn1; pn2 = nn2;
    }
    if (G == 0){ CstAll[m][L15] = Cacc; SfinAll[m][L15] = S; }
  };

  // ---------------- consumer: hedge (unroll-2) + payoff for maturity m ----------------
  auto consume = [&](int m){
    f16x8 aH[3][4][2];  f16x4 bHr[3][4];  f16x8 wh0r[2][3];
#pragma unroll
    for (int L = 0; L < 3; ++L){
      const float* W = (L==0)?hW1:(L==1)?hW2:hW3;
      const float* B = (L==0)?hb1:(L==1)?hb2:hb3;
#pragma unroll
      for (int mt = 0; mt < 4; ++mt){
#pragma unroll
        for (int kt = 0; kt < 2; ++kt){
          const float* src = W + (size_t)m*4096 + (16*mt + L15)*64 + kt*32 + G*8;
          aH[L][mt][kt] = cvt88(*(const float4*)src, *(const float4*)(src+4));
        }
        bHr[L][mt] = cvt4(*(const float4*)(B + m*64 + mt*16 + 4*G));
      }
    }
#pragma unroll
    for (int kt = 0; kt < 2; ++kt){
      f16x8 wt, ws, bz;
#pragma unroll
      for (int j = 0; j < 8; ++j){
        const int o = kt*32 + G*8 + j;
        wt[j]=(f16)hW0[m*128 + o*2];
        ws[j]=(f16)hW0[m*128 + o*2 + 1];
        bz[j]=(f16)hb0[m*64 + o];
      }
      wh0r[kt][0]=wt; wh0r[kt][1]=ws; wh0r[kt][2]=bz;
    }
    float Gacc[16];
#pragma unroll
    for (int j = 0; j < 16; ++j) Gacc[j] = 0.f;
    const int b = m & 1;

#pragma unroll 1
    for (int s = 0; s < PERS; s += 2){
      const float t0 = (float)(m*PERS + s    ) * DTf;
      const float t1 = (float)(m*PERS + s + 1) * DTf;
      const float S0 = SP[b][s][L15],   c0 = CP[b][s][L15];
      const float S1 = SP[b][s+1][L15], c1 = CP[b][s+1][L15];
      const f16 th0=(f16)t0, Sh0=(f16)S0, th1=(f16)t1, Sh1=(f16)S1;
      f16x8 ba0 = relu8(wh0r[0][0]*th0 + wh0r[0][1]*Sh0 + wh0r[0][2]);
      f16x8 ba1 = relu8(wh0r[1][0]*th0 + wh0r[1][1]*Sh0 + wh0r[1][2]);
      f16x8 bb0 = relu8(wh0r[0][0]*th1 + wh0r[0][1]*Sh1 + wh0r[0][2]);
      f16x8 bb1 = relu8(wh0r[1][0]*th1 + wh0r[1][1]*Sh1 + wh0r[1][2]);
#pragma unroll
      for (int mt = 0; mt < 4; ++mt){
        f32x4 aa = {(float)bHr[0][mt][0],(float)bHr[0][mt][1],(float)bHr[0][mt][2],(float)bHr[0][mt][3]};
        f32x4 ab = aa;
        aa = __builtin_amdgcn_mfma_f32_16x16x32_f16(aH[0][mt][0], ba0, aa, 0,0,0);
        aa = __builtin_amdgcn_mfma_f32_16x16x32_f16(aH[0][mt][1], ba1, aa, 0,0,0);
        ab = __builtin_amdgcn_mfma_f32_16x16x32_f16(aH[0][mt][0], bb0, ab, 0,0,0);
        ab = __builtin_amdgcn_mfma_f32_16x16x32_f16(aH[0][mt][1], bb1, ab, 0,0,0);
        f16x4 oa, ob;
#pragma unroll
        for (int r = 0; r < 4; ++r){ oa[r]=(f16)fmaxf(aa[r],0.f); ob[r]=(f16)fmaxf(ab[r],0.f); }
        *(f16x4*)&bbH[0][L15*HSTR + mt*16 + 4*G] = oa;
        *(f16x4*)&bbH[2][L15*HSTR + mt*16 + 4*G] = ob;
      }
      LDS_FENCE();
      f16x8 xa0 = *(const f16x8*)&bbH[0][L15*HSTR +      G*8];
      f16x8 xa1 = *(const f16x8*)&bbH[0][L15*HSTR + 32 + G*8];
      f16x8 xb0 = *(const f16x8*)&bbH[2][L15*HSTR +      G*8];
      f16x8 xb1 = *(const f16x8*)&bbH[2][L15*HSTR + 32 + G*8];
#pragma unroll
      for (int mt = 0; mt < 4; ++mt){
        f32x4 aa = {(float)bHr[1][mt][0],(float)bHr[1][mt][1],(float)bHr[1][mt][2],(float)bHr[1][mt][3]};
        f32x4 ab = aa;
        aa = __builtin_amdgcn_mfma_f32_16x16x32_f16(aH[1][mt][0], xa0, aa, 0,0,0);
        aa = __builtin_amdgcn_mfma_f32_16x16x32_f16(aH[1][mt][1], xa1, aa, 0,0,0);
        ab = __builtin_amdgcn_mfma_f32_16x16x32_f16(aH[1][mt][0], xb0, ab, 0,0,0);
        ab = __builtin_amdgcn_mfma_f32_16x16x32_f16(aH[1][mt][1], xb1, ab, 0,0,0);
        f16x4 oa, ob;
#pragma unroll
        for (int r = 0; r < 4; ++r){ oa[r]=(f16)fmaxf(aa[r],0.f); ob[r]=(f16)fmaxf(ab[r],0.f); }
        *(f16x4*)&bbH[1][L15*HSTR + mt*16 + 4*G] = oa;
        *(f16x4*)&bbH[3][L15*HSTR + mt*16 + 4*G] = ob;
      }
      LDS_FENCE();
      xa0 = *(const f16x8*)&bbH[1][L15*HSTR +      G*8];
      xa1 = *(const f16x8*)&bbH[1][L15*HSTR + 32 + G*8];
      xb0 = *(const f16x8*)&bbH[3][L15*HSTR +      G*8];
      xb1 = *(const f16x8*)&bbH[3][L15*HSTR + 32 + G*8];
#pragma unroll
      for (int mt = 0; mt < 4; ++mt){
        f32x4 aa = {(float)bHr[2][mt][0],(float)bHr[2][mt][1],(float)bHr[2][mt][2],(float)bHr[2][mt][3]};
        f32x4 ab = aa;
        aa = __builtin_amdgcn_mfma_f32_16x16x32_f16(aH[2][mt][0], xa0, aa, 0,0,0);
        aa = __builtin_amdgcn_mfma_f32_16x16x32_f16(aH[2][mt][1], xa1, aa, 0,0,0);
        ab = __builtin_amdgcn_mfma_f32_16x16x32_f16(aH[2][mt][0], xb0, ab, 0,0,0);
        ab = __builtin_amdgcn_mfma_f32_16x16x32_f16(aH[2][mt][1], xb1, ab, 0,0,0);
#pragma unroll
        for (int r = 0; r < 4; ++r)
          Gacc[mt*4+r] += c0*fmaxf(aa[r],0.f) + c1*fmaxf(ab[r],0.f);
      }
    }

    // stash G (wave1-private) and run the payoff for maturity m
#pragma unroll
    for (int mt = 0; mt < 4; ++mt)
#pragma unroll
      for (int r = 0; r < 4; ++r)
        Gsave[m][mt*16 + 4*G + r][L15] = Gacc[mt*4+r];
    LDS_FENCE();

    const float discm = (float)exp(-0.05*(2.0/96.0)*(double)(PERS*(m+1)));
    const float Sfin  = SfinAll[m][L15];
#pragma unroll 1
    for (int mt = 0; mt < 13; ++mt){
      const int ksr = min(16*mt + L15, 200);
      f32x4 acc = {0.f, 0.f, 0.f, 0.f};
#pragma unroll 1
      for (int q = 0; q <= m; ++q){
        f16x8 Bq0, Bq1;
#pragma unroll
        for (int j = 0; j < 8; ++j){
          Bq0[j] = (f16)(Gsave[q][     G*8 + j][L15] * GSC);
          Bq1[j] = (f16)(Gsave[q][32 + G*8 + j][L15] * GSC);
        }
        const float* ap0 = hW4 + (size_t)(q*804 + ksr*4 + m)*64 +      G*8;
        const float* ap1 = hW4 + (size_t)(q*804 + ksr*4 + m)*64 + 32 + G*8;
        acc = __builtin_amdgcn_mfma_f32_16x16x32_f16(cvt88(*(const float4*)ap0, *(const float4*)(ap0+4)), Bq0, acc, 0,0,0);
        acc = __builtin_amdgcn_mfma_f32_16x16x32_f16(cvt88(*(const float4*)ap1, *(const float4*)(ap1+4)), Bq1, acc, 0,0,0);
      }
#pragma unroll
      for (int r = 0; r < 4; ++r){
        const int k2  = 16*mt + 4*G + r;
        const int k2c = min(k2, 200);
        float ac = acc[r] * GUNSC;
#pragma unroll 1
        for (int q = 0; q <= m; ++q)
          ac = fmaf(hb4[q*804 + k2c*4 + m], CstAll[q][L15], ac);
        const float pay = discm*fmaxf(Sfin - strikes[k2c], 0.f) - ac;
        float s1 = pay, s2 = pay*pay;
        s1 += __shfl_xor(s1,1); s1 += __shfl_xor(s1,2);
        s1 += __shfl_xor(s1,4); s1 += __shfl_xor(s1,8);
        s2 += __shfl_xor(s2,1); s2 += __shfl_xor(s2,2);
        s2 += __shfl_xor(s2,4); s2 += __shfl_xor(s2,8);
        if (L15 == 0 && k2 < NK){
          part1[(size_t)(m*NK + k2)*NPG + blockIdx.x] = s1;
          part2[(size_t)(m*NK + k2)*NPG + blockIdx.x] = s2;
        }
      }
    }
  };

  // ---------------- 5 uniform phases: produce(p) || consume(p-1) ----------------
#pragma unroll 1
  for (int ph = 0; ph < 5; ++ph){
    if (wv == 0 && ph < 4)  produce(ph);
    if (wv == 1 && ph >= 1) consume(ph - 1);
    __syncthreads();
  }
}

__global__ __launch_bounds__(256)
void finalize_kernel(const float* __restrict__ part1,
                     const float* __restrict__ part2,
                     float* __restrict__ out)
{
  const int j   = blockIdx.x;          // j = m*NK + k
  const int m   = j / NK, k = j % NK;
  const int tid = threadIdx.x;
  double s1 = (double)part1[(size_t)j*NPG + tid]
            + (double)part1[(size_t)j*NPG + 256 + tid];
  double s2 = (double)part2[(size_t)j*NPG + tid]
            + (double)part2[(size_t)j*NPG + 256 + tid];
#pragma unroll
  for (int d = 32; d > 0; d >>= 1){
    s1 += __shfl_down(s1, d, 64);
    s2 += __shfl_down(s2, d, 64);
  }
  __shared__ double r1[4], r2[4];
  if ((tid & 63) == 0){ r1[tid>>6] = s1; r2[tid>>6] = s2; }
  __syncthreads();
  if (tid == 0){
    const double t1 = r1[0]+r1[1]+r1[2]+r1[3];
    const double t2 = r2[0]+r2[1]+r2[2]+r2[3];
    const double mean = t1 / 8192.0;
    const double var  = (t2 - t1*t1/8192.0) / 8191.0;   // ddof=1
    out[k*NMAT + m]            = (float)mean;
    out[NK*NMAT + k*NMAT + m]  = (float)var;
  }
}

extern "C" void kernel_launch(void* const* d_in, const int* in_sizes, int n_in,
                              void* d_out, int out_size, void* d_ws, size_t ws_size,
                              hipStream_t stream)
{
  (void)in_sizes; (void)n_in; (void)out_size; (void)ws_size;
  const float* nW0 = (const float*)d_in[0];
  const float* nb0 = (const float*)d_in[1];
  const float* nW1 = (const float*)d_in[2];
  const float* nb1 = (const float*)d_in[3];
  const float* nW2 = (const float*)d_in[4];
  const float* nb2 = (const float*)d_in[5];
  const float* nW3 = (const float*)d_in[6];
  const float* nb3 = (const float*)d_in[7];
  const float* hW0 = (const float*)d_in[8];
  const float* hb0 = (const float*)d_in[9];
  const float* hW1 = (const float*)d_in[10];
  const float* hb1 = (const float*)d_in[11];
  const float* hW2 = (const float*)d_in[12];
  const float* hb2 = (const float*)d_in[13];
  const float* hW3 = (const float*)d_in[14];
  const float* hb3 = (const float*)d_in[15];
  const float* hW4 = (const float*)d_in[16];
  const float* hb4 = (const float*)d_in[17];
  const float* rho = (const float*)d_in[18];
  const float* V0  = (const float*)d_in[19];
  const float* strikes = (const float*)d_in[20];
  const float* noise1  = (const float*)d_in[21];
  const float* noise2  = (const float*)d_in[22];

  float* part1 = (float*)d_ws;
  float* part2 = part1 + (size_t)NMAT*NK*NPG;

  sde_kernel<<<NBLOCKS, TPB, 0, stream>>>(nW0, nb0, nW1, nb1, nW2, nb2, nW3, nb3,
                                          hW0, hb0, hW1, hb1, hW2, hb2, hW3, hb3,
                                          hW4, hb4, rho, V0, strikes, noise1, noise2,
                                          part1, part2);

  finalize_kernel<<<NMAT*NK, 256, 0, stream>>>(part1, part2, (float*)d_out);
}